// Round 5
// baseline (270.159 us; speedup 1.0000x reference)
//
#include <hip/hip_runtime.h>

#define NN 2048   // factor dim
#define KK 16     // nonzeros per row

// ---------------------------------------------------------------------------
// Fused compose: mcl = scaling * (W0 @ W1 @ W2) in coefficient form,
// residue-major: mcl[((s*16 + j)*16) + i] for col c = s + 128*j, coefficient
// of x[((c-3) mod 128) + 128*i].  (Verified in Round 4.)
// ---------------------------------------------------------------------------
__global__ __launch_bounds__(128) void sfd_compose(const float* __restrict__ v0,
                                                   const float* __restrict__ v1,
                                                   const float* __restrict__ v2,
                                                   const float* __restrict__ scaling,
                                                   float* __restrict__ mcl) {
  int tid = blockIdx.x * 128 + threadIdx.x;   // 32768 threads: (c, i)
  int c = tid >> 4;
  int i = tid & 15;

  int A  = (c + NN - 3) & (NN - 1);           // (c-3) mod N
  int s1 = A & 127;
  int T0 = A >> 7;
  int rx = s1 + (i << 7);

  // Pre-rotated v0 row: vr[m] = v0[rx*16 + ((T0 - i - m) & 15)]
  float vr[16];
#pragma unroll
  for (int m = 0; m < 16; ++m)
    vr[m] = v0[rx * 16 + ((T0 - i - m) & 15)];

  float acc = 0.f;
#pragma unroll 4
  for (int k2 = 0; k2 < 16; ++k2) {
    int r1 = (c + NN - 2 - (k2 << 7)) & (NN - 1);
    int cm = (r1 + NN - 1) & (NN - 1);
    float w = 0.f;
#pragma unroll
    for (int k1 = 0; k1 < 16; ++k1) {
      int r0 = (cm - (k1 << 7)) & (NN - 1);
      w = fmaf(v1[r0 * 16 + k1], vr[(k1 + k2) & 15], w);
    }
    acc = fmaf(v2[r1 * 16 + k2], w, acc);
  }
  int s = c & 127;
  int j = c >> 7;
  mcl[(s * 16 + j) * 16 + i] = acc * scaling[0];
}

// ---------------------------------------------------------------------------
// Raw workgroup barrier WITHOUT the __syncthreads vmcnt(0) drain.
// Semantics: all DS ops (write-publish AND read-retire for buffer reuse) must
// be complete -> lgkmcnt(0).  Outstanding GLOBAL loads/stores target private
// VGPRs / out[] only -> no cross-wave hazard -> legally stay in flight across
// the barrier (this is the whole point: T4 counted waits).  Memory-clobber
// asms fence compiler-level reordering of LDS ops across the barrier.
// ---------------------------------------------------------------------------
__device__ __forceinline__ void sfd_barrier() {
  asm volatile("s_waitcnt lgkmcnt(0)" ::: "memory");
  __builtin_amdgcn_s_barrier();
  asm volatile("" ::: "memory");
}

// ---------------------------------------------------------------------------
// Apply-stage helpers (all indices compile-time-unrollable).
// ---------------------------------------------------------------------------
__device__ __forceinline__ void sfd_loadq(float4 (&pf)[4], const float* __restrict__ x,
                                          int rb, int w0, int t) {
#pragma unroll
  for (int q = 0; q < 4; ++q) {
    int idx = t + (q << 8);                 // 0..1023 = rr*128 + ig*32 + uu
    int uu = idx & 31;
    int ig = (idx >> 5) & 3;                // i-group (4 i's)
    int rr = idx >> 7;                      // 0..7
    const float* xrow = x + (size_t)(rb + rr) * NN;
    int cb = w0 + uu + (ig << 9);           // w0+uu+128*(4*ig)
    pf[q].x = xrow[cb & (NN - 1)];
    pf[q].y = xrow[(cb + 128) & (NN - 1)];
    pf[q].z = xrow[(cb + 256) & (NN - 1)];
    pf[q].w = xrow[(cb + 384) & (NN - 1)];
  }
}

__device__ __forceinline__ void sfd_writeq(const float4 (&pf)[4], float* xs, int t) {
#pragma unroll
  for (int q = 0; q < 4; ++q) {
    int idx = t + (q << 8);
    int uu = idx & 31;
    int ig = (idx >> 5) & 3;
    int rr = idx >> 7;
    *(float4*)(xs + (rr * 32 + uu) * 20 + (ig << 2)) = pf[q];
  }
}

__device__ __forceinline__ void sfd_ldr(float (&xv)[16], const float* xs, int u, int r) {
  const float4* xr = (const float4*)(xs + (r * 32 + u) * 20);
  *(float4*)(xv + 0)  = xr[0];
  *(float4*)(xv + 4)  = xr[1];
  *(float4*)(xv + 8)  = xr[2];
  *(float4*)(xv + 12) = xr[3];
}

__device__ __forceinline__ void sfd_fma(const float (&xv)[16],
                                        const float (&mc0)[16], const float (&mc1)[16],
                                        float bi0, float bi1,
                                        int row, int c0, int c1,
                                        float* __restrict__ out) {
  float acc0 = bi0, acc1 = bi1;
#pragma unroll
  for (int i = 0; i < 16; ++i) {
    acc0 = fmaf(xv[i], mc0[i], acc0);
    acc1 = fmaf(xv[i], mc1[i], acc1);
  }
  size_t ob = (size_t)row * NN;
  __builtin_nontemporal_store(fmaxf(acc0, 0.f), &out[ob + c0]);
  __builtin_nontemporal_store(fmaxf(acc1, 0.f), &out[ob + c1]);
}

// Compute 8 rows with software-pipelined LDS reads: read r+1's 4 ds_read_b128
// while r's 32 FMAs run (xvA/xvB alternate, all indices static -> no scratch).
__device__ __forceinline__ void sfd_compute(const float* xs, int u,
                                            const float (&mc0)[16], const float (&mc1)[16],
                                            float bi0, float bi1,
                                            int rb, int c0, int c1,
                                            float* __restrict__ out) {
  float xvA[16], xvB[16];
  sfd_ldr(xvA, xs, u, 0);
#pragma unroll
  for (int rp = 0; rp < 4; ++rp) {
    sfd_ldr(xvB, xs, u, 2 * rp + 1);
    sfd_fma(xvA, mc0, mc1, bi0, bi1, rb + 2 * rp, c0, c1, out);
    if (rp < 3) sfd_ldr(xvA, xs, u, 2 * rp + 2);
    sfd_fma(xvB, mc0, mc1, bi0, bi1, rb + 2 * rp + 1, c0, c1, out);
  }
}

// ---------------------------------------------------------------------------
// Apply: out[b][c] = relu( sum_i mcl[c][i] * x[b][(c-3)%128 + 128*i] + bias[c] )
// Block: strip of 32 residues (512 cols) x 32 batch rows; grid (4, 512).
// Thread (u=t&31, jp=t>>5) -> 2 cols c = S0+u+128*(2jp+{0,1}); 2x16
// coefficients in registers (rotated by `shift` to absorb the mod-128 wrap).
// LDS xs[buf][r][u][i] stride 20 floats: ds_read_b128, conflict-free (meas. 0).
//
// Round-5: the R3/R4 pipelines never pipelined — __syncthreads() drains
// vmcnt(0) before s_barrier, force-retiring the prefetch loads at every
// barrier.  sfd_barrier() (lgkmcnt(0) + raw s_barrier) leaves the 16
// prefetch loads in flight through the whole next chunk's compute, which is
// the actual T14/T4 schedule.  Plus: r-loop LDS reads software-pipelined.
//
// launch_bounds(256,4): 128-VGPR budget (R2 showed the 64-VGPR cap spills the
// prefetch regs).  LDS 40 KiB + (256,4) -> 4 blocks/CU, 16 waves.
// ---------------------------------------------------------------------------
__global__ __launch_bounds__(256, 4) void sfd_apply(const float* __restrict__ x,
                                                    const float* __restrict__ mcl,
                                                    const float* __restrict__ bias,
                                                    float* __restrict__ out) {
  const int S0 = blockIdx.x << 5;             // strip base residue: 0,32,64,96
  const int b0 = blockIdx.y << 5;             // 32 batch rows per block
  const int t = threadIdx.x;
  const int u = t & 31;
  const int jp = t >> 5;                      // 0..7
  const int s = S0 + u;                       // residue (= col mod 128), < 128
  const int j0 = jp << 1;
  const int w0 = (S0 + 125) & 127;            // (S0 - 3) mod 128
  const int shift = (w0 + u) >> 7;            // 1 iff this thread's window wraps

  // 2x16 coefficients into registers, rotated by `shift`:
  // LDS slot i holds x[(s-3)%128 + 128*((i+shift)&15)].
  float mc0[16], mc1[16];
  {
    const float* r0p = mcl + ((s * 16 + j0) << 4);
#pragma unroll
    for (int i = 0; i < 16; ++i) {
      int ic = (i + shift) & 15;
      mc0[i] = r0p[ic];
      mc1[i] = r0p[16 + ic];
    }
  }
  const int c0 = s + (j0 << 7);
  const int c1 = c0 + 128;
  const float bi0 = bias[c0];
  const float bi1 = bias[c1];

  __shared__ float xs[2][8 * 32 * 20];        // 2 x 20480 B double buffer

  float4 pfA[4], pfB[4];

  // Prologue: stage chunk0 into buf0, start chunk1 loads.
  sfd_loadq(pfA, x, b0 + 0,  w0, t);
  sfd_writeq(pfA, xs[0], t);                  // compiler waits vmcnt for pfA
  sfd_loadq(pfB, x, b0 + 8,  w0, t);          // stays in flight across barrier
  sfd_barrier();                              // buf0 ready (lgkm only!)

  // Chunk 0 (read buf0); stage chunk1 -> buf1; issue chunk2 loads.
  sfd_compute(xs[0], u, mc0, mc1, bi0, bi1, b0 + 0,  c0, c1, out);
  sfd_writeq(pfB, xs[1], t);                  // vmcnt(pfB) hidden by compute
  sfd_loadq(pfA, x, b0 + 16, w0, t);
  sfd_barrier();                              // buf1 ready, buf0 free

  // Chunk 1 (read buf1); stage chunk2 -> buf0; issue chunk3 loads.
  sfd_compute(xs[1], u, mc0, mc1, bi0, bi1, b0 + 8,  c0, c1, out);
  sfd_writeq(pfA, xs[0], t);
  sfd_loadq(pfB, x, b0 + 24, w0, t);
  sfd_barrier();                              // buf0 ready, buf1 free

  // Chunk 2 (read buf0); stage chunk3 -> buf1.
  sfd_compute(xs[0], u, mc0, mc1, bi0, bi1, b0 + 16, c0, c1, out);
  sfd_writeq(pfB, xs[1], t);
  sfd_barrier();                              // buf1 ready

  // Chunk 3 (read buf1).
  sfd_compute(xs[1], u, mc0, mc1, bi0, bi1, b0 + 24, c0, c1, out);
}

extern "C" void kernel_launch(void* const* d_in, const int* in_sizes, int n_in,
                              void* d_out, int out_size, void* d_ws, size_t ws_size,
                              hipStream_t stream) {
  // 0:x 1:vals0 2:vals1 3:vals2 4:rows0 5:cols0 6:rows1 7:cols1 8:rows2 9:cols2
  // 10:scaling 11:bias
  const float* x       = (const float*)d_in[0];
  const float* v0      = (const float*)d_in[1];
  const float* v1      = (const float*)d_in[2];
  const float* v2      = (const float*)d_in[3];
  const float* scaling = (const float*)d_in[10];
  const float* bias    = (const float*)d_in[11];
  float* out = (float*)d_out;

  float* mcl = (float*)d_ws;          // 2048*16 floats = 128 KiB

  const int B = in_sizes[0] / NN;     // 16384

  hipLaunchKernelGGL(sfd_compose, dim3(256), dim3(128), 0, stream, v0, v1, v2, scaling, mcl);
  hipLaunchKernelGGL(sfd_apply, dim3(4, B >> 5), dim3(256), 0, stream, x, mcl, bias, out);
}

// Round 6
// 269.112 us; speedup vs baseline: 1.0039x; 1.0039x over previous
//
#include <hip/hip_runtime.h>

#define NN 2048   // factor dim
#define KK 16     // nonzeros per row

// ---------------------------------------------------------------------------
// Fused compose: mcl = scaling * (W0 @ W1 @ W2) in coefficient form,
// residue-major: mcl[((s*16 + j)*16) + i] for col c = s + 128*j, coefficient
// of x[((c-3) mod 128) + 128*i].  (Verified in Rounds 4/5.)
// ---------------------------------------------------------------------------
__global__ __launch_bounds__(128) void sfd_compose(const float* __restrict__ v0,
                                                   const float* __restrict__ v1,
                                                   const float* __restrict__ v2,
                                                   const float* __restrict__ scaling,
                                                   float* __restrict__ mcl) {
  int tid = blockIdx.x * 128 + threadIdx.x;   // 32768 threads: (c, i)
  int c = tid >> 4;
  int i = tid & 15;

  int A  = (c + NN - 3) & (NN - 1);           // (c-3) mod N
  int s1 = A & 127;
  int T0 = A >> 7;
  int rx = s1 + (i << 7);

  // Pre-rotated v0 row: vr[m] = v0[rx*16 + ((T0 - i - m) & 15)]
  float vr[16];
#pragma unroll
  for (int m = 0; m < 16; ++m)
    vr[m] = v0[rx * 16 + ((T0 - i - m) & 15)];

  float acc = 0.f;
#pragma unroll 4
  for (int k2 = 0; k2 < 16; ++k2) {
    int r1 = (c + NN - 2 - (k2 << 7)) & (NN - 1);
    int cm = (r1 + NN - 1) & (NN - 1);
    float w = 0.f;
#pragma unroll
    for (int k1 = 0; k1 < 16; ++k1) {
      int r0 = (cm - (k1 << 7)) & (NN - 1);
      w = fmaf(v1[r0 * 16 + k1], vr[(k1 + k2) & 15], w);
    }
    acc = fmaf(v2[r1 * 16 + k2], w, acc);
  }
  int s = c & 127;
  int j = c >> 7;
  mcl[(s * 16 + j) * 16 + i] = acc * scaling[0];
}

// ---------------------------------------------------------------------------
// Apply v6 — FULL-ROW decomposition (Round-6).
//
// Round-5 post-mortem: apply is pinned at 3.1 TB/s (= half the 6.3 TB/s copy
// ceiling) regardless of occupancy (65%..38%) or pipeline structure (4
// schedule variants, all 85-91 us).  Theory: the 32-residue strip partition
// makes every block's read stream 128B-used-per-512B (window stride 128
// floats) and its write stream 128B-per-512B (32-col pieces every 128 cols),
// split across 4 XCDs -> DRAM row-buffer/burst efficiency ~50%.  A pattern
// wall is exactly what is insensitive to scheduling.
//
// v6: block = 32 batch rows x ALL 2048 columns.  512 threads; thread
// (u=t&127, g=t>>7) owns 4 cols c = u + 128*(4g+jj), jj=0..3 — all sharing
// one residue window W=(u-3)%128, so 16 LDS reads feed 4 accumulators
// (64 coeff VGPRs).  Consequences:
//   - staging = contiguous 64 KB global->LDS copy per 8-row chunk
//     (float4-coalesced, linear LDS, conflict-free b128 writes)
//   - out writes = full contiguous 8 KB rows
//   - no rotation/shift logic: full row in LDS -> direct xs[W + 128*i]
//   - x read once, out written once (traffic unchanged)
// Simple 2-barrier chunk loop (R3-R5 proved schedule games are worthless
// here).  (512,4): 128-VGPR cap, est ~111 used (mc 64 + xv 16 + pf 16 +
// misc), 64 KB LDS -> 2 blocks/CU = 16 waves.
// ---------------------------------------------------------------------------
__global__ __launch_bounds__(512, 4) void sfd_apply(const float* __restrict__ x,
                                                    const float* __restrict__ mcl,
                                                    const float* __restrict__ bias,
                                                    float* __restrict__ out) {
  const int t  = threadIdx.x;
  const int u  = t & 127;                     // residue (col mod 128)
  const int g  = t >> 7;                      // 0..3  (j-group base 4g)
  const int rb = blockIdx.x << 5;             // 32 batch rows per block
  const int W  = (u + 125) & 127;             // (c-3) mod 128, same for all 4 cols

  // 4x16 coefficients: 64 CONSECUTIVE floats at mcl + u*256 + g*64
  // (cols c = u+128*(4g+jj): mcl[(u*16 + 4g+jj)*16 + i])
  float mc[4][16];
  {
    const float4* mp = (const float4*)(mcl + (size_t)u * 256 + (size_t)g * 64);
#pragma unroll
    for (int q = 0; q < 16; ++q) {
      float4 v = mp[q];
      mc[q >> 2][(q & 3) * 4 + 0] = v.x;
      mc[q >> 2][(q & 3) * 4 + 1] = v.y;
      mc[q >> 2][(q & 3) * 4 + 2] = v.z;
      mc[q >> 2][(q & 3) * 4 + 3] = v.w;
    }
  }
  const int cb = u + (g << 9);                // col base u + 512g; cols cb + 128*jj
  float bi[4];
#pragma unroll
  for (int jj = 0; jj < 4; ++jj) bi[jj] = bias[cb + (jj << 7)];

  __shared__ float xs[8 * 2048];              // 64 KiB: 8 full rows

  for (int ch = 0; ch < 4; ++ch) {
    const float4* xc = (const float4*)(x + ((size_t)(rb + (ch << 3)) << 11));
    // ---- stage 8 rows = 64 KB contiguous, 8 float4/thread (two groups of 4
    //      to bound live registers) ----
    {
      float4 pf[4];
#pragma unroll
      for (int q = 0; q < 4; ++q) pf[q] = xc[t + (q << 9)];
#pragma unroll
      for (int q = 0; q < 4; ++q) ((float4*)xs)[t + (q << 9)] = pf[q];
#pragma unroll
      for (int q = 0; q < 4; ++q) pf[q] = xc[t + ((q + 4) << 9)];
#pragma unroll
      for (int q = 0; q < 4; ++q) ((float4*)xs)[t + ((q + 4) << 9)] = pf[q];
    }
    __syncthreads();
    // ---- compute 8 rows x 4 cols per thread ----
#pragma unroll 1
    for (int r = 0; r < 8; ++r) {
      const float* xr = xs + (r << 11) + W;
      float xv[16];
#pragma unroll
      for (int i = 0; i < 16; ++i) xv[i] = xr[i << 7];
      float a0 = bi[0], a1 = bi[1], a2 = bi[2], a3 = bi[3];
#pragma unroll
      for (int i = 0; i < 16; ++i) {
        a0 = fmaf(xv[i], mc[0][i], a0);
        a1 = fmaf(xv[i], mc[1][i], a1);
        a2 = fmaf(xv[i], mc[2][i], a2);
        a3 = fmaf(xv[i], mc[3][i], a3);
      }
      size_t ob = ((size_t)(rb + (ch << 3) + r) << 11) + cb;
      __builtin_nontemporal_store(fmaxf(a0, 0.f), &out[ob]);
      __builtin_nontemporal_store(fmaxf(a1, 0.f), &out[ob + 128]);
      __builtin_nontemporal_store(fmaxf(a2, 0.f), &out[ob + 256]);
      __builtin_nontemporal_store(fmaxf(a3, 0.f), &out[ob + 384]);
    }
    __syncthreads();
  }
}

extern "C" void kernel_launch(void* const* d_in, const int* in_sizes, int n_in,
                              void* d_out, int out_size, void* d_ws, size_t ws_size,
                              hipStream_t stream) {
  // 0:x 1:vals0 2:vals1 3:vals2 4:rows0 5:cols0 6:rows1 7:cols1 8:rows2 9:cols2
  // 10:scaling 11:bias
  const float* x       = (const float*)d_in[0];
  const float* v0      = (const float*)d_in[1];
  const float* v1      = (const float*)d_in[2];
  const float* v2      = (const float*)d_in[3];
  const float* scaling = (const float*)d_in[10];
  const float* bias    = (const float*)d_in[11];
  float* out = (float*)d_out;

  float* mcl = (float*)d_ws;          // 2048*16 floats = 128 KiB

  const int B = in_sizes[0] / NN;     // 16384

  hipLaunchKernelGGL(sfd_compose, dim3(256), dim3(128), 0, stream, v0, v1, v2, scaling, mcl);
  hipLaunchKernelGGL(sfd_apply, dim3(B >> 5), dim3(512), 0, stream, x, mcl, bias, out);
}